// Round 12
// baseline (542.540 us; speedup 1.0000x reference)
//
#include <hip/hip_runtime.h>

#define B_ 256
#define K_ 512
#define D_ 64
#define KD_ 576
#define LOG2E 1.44269504088896340736f

// Diagnostic rep counts (idempotent re-execution to make each dispatch visible
// in the duration-sorted top-5 above the ~41us harness fills):
#define REP_S   32
#define REP_EF  16
#define REP_M   16
#define REP_FIN 32

typedef float v4f __attribute__((ext_vector_type(4)));
typedef short bf16x8 __attribute__((ext_vector_type(8)));
typedef float f32x16 __attribute__((ext_vector_type(16)));

#define ZERO16 {0.f,0.f,0.f,0.f,0.f,0.f,0.f,0.f,0.f,0.f,0.f,0.f,0.f,0.f,0.f,0.f}

__device__ __forceinline__ float fexp2(float x) {
#if __has_builtin(__builtin_amdgcn_exp2f)
    return __builtin_amdgcn_exp2f(x);
#else
    float r; asm("v_exp_f32 %0, %1" : "=v"(r) : "v"(x)); return r;
#endif
}
__device__ __forceinline__ float frcp(float x) {
#if __has_builtin(__builtin_amdgcn_rcpf)
    return __builtin_amdgcn_rcpf(x);
#else
    float r; asm("v_rcp_f32 %0, %1" : "=v"(r) : "v"(x)); return r;
#endif
}
__device__ __forceinline__ float fsig(float x) {
    return frcp(1.0f + fexp2(-LOG2E * x));
}
__device__ __forceinline__ ushort f2bf(float f) {
    union { float f; unsigned u; } v; v.f = f;
    return (ushort)((v.u + 0x7FFFu + ((v.u >> 16) & 1u)) >> 16);
}
__device__ __forceinline__ bf16x8 ldcvt8(const float* p) {
    float4 a = *(const float4*)p;
    float4 b = *(const float4*)(p + 4);
    bf16x8 r;
    r[0] = (short)f2bf(a.x); r[1] = (short)f2bf(a.y);
    r[2] = (short)f2bf(a.z); r[3] = (short)f2bf(a.w);
    r[4] = (short)f2bf(b.x); r[5] = (short)f2bf(b.y);
    r[6] = (short)f2bf(b.z); r[7] = (short)f2bf(b.w);
    return r;
}

// ---------------------------------------------------------------------------
// kS (64 blocks x 256), body = R11-verbatim, x REP_S
// ---------------------------------------------------------------------------
__global__ void __launch_bounds__(256) kS(const int* __restrict__ sid,
                                          const int* __restrict__ eid,
                                          const float* __restrict__ stu_t,
                                          const float* __restrict__ exer_t,
                                          const float* __restrict__ kn_t,
                                          ushort* __restrict__ Sbu) {
    const int bid = blockIdx.x, t = threadIdx.x;
    const int l = t & 63, w = t >> 6;
    const int dk = (l >> 5) * 8;
    for (int rep = 0; rep < REP_S; ++rep) {
        asm volatile("" ::: "memory");
        const int tab = bid >> 5, bt = (bid >> 3) & 3, nt = bid & 7;
        const int b0 = bt * 64, n0 = nt * 64;
        const int brow = b0 + (w & 1) * 32 + (l & 31);
        const int ncol = n0 + (w >> 1) * 32 + (l & 31);
        const int id = (tab ? eid : sid)[brow];
        const float* ar = (tab ? exer_t : stu_t) + (size_t)id * D_;
        const float* br = kn_t + (size_t)ncol * D_;
        f32x16 acc = ZERO16;
#pragma unroll
        for (int kk = 0; kk < 4; kk++) {
            bf16x8 a = ldcvt8(ar + kk * 16 + dk);
            bf16x8 b = ldcvt8(br + kk * 16 + dk);
            acc = __builtin_amdgcn_mfma_f32_32x32x16_bf16(a, b, acc, 0, 0, 0);
        }
        ushort* So = Sbu + (size_t)tab * B_ * K_;
#pragma unroll
        for (int r = 0; r < 16; r++) {
            const int row = (r & 3) + 8 * (r >> 2) + 4 * (l >> 5);
            So[(size_t)(b0 + (w & 1) * 32 + row) * K_ + ncol] = f2bf(fsig(acc[r]));
        }
    }
}

// ---------------------------------------------------------------------------
// kEF (384 blocks x 256), body = R11-verbatim, x REP_EF
// ---------------------------------------------------------------------------
__global__ void __launch_bounds__(256) kEF(const ushort* __restrict__ Sbu,
                                           const float* __restrict__ W1,
                                           const float* __restrict__ W2,
                                           const float* __restrict__ kn_t,
                                           float* __restrict__ E,
                                           float* __restrict__ FT1,
                                           float* __restrict__ FT2) {
    __shared__ float shm[4224];
    const int bid = blockIdx.x, t = threadIdx.x;
    const int l = t & 63, w = t >> 6;
    for (int rep = 0; rep < REP_EF; ++rep) {
        asm volatile("" ::: "memory");
        if (bid < 256) {
            const int mat = bid >> 7, bt = (bid >> 4) & 7, nt = bid & 15;
            const int b0 = bt * 32, n0 = nt * 32;
            const int arow = b0 + (l & 31);
            const int nrow = n0 + (l & 31);
            const int koff = w * 128 + (l >> 5) * 8;
            const short* Sp = (const short*)Sbu + (size_t)(mat * B_ + arow) * K_ + koff;
            const float* Wp = (mat ? W2 : W1) + (size_t)nrow * KD_ + koff;
            f32x16 acc = ZERO16;
#pragma unroll
            for (int kk = 0; kk < 8; kk++) {
                bf16x8 a = *(const bf16x8*)(Sp + kk * 16);
                bf16x8 b = ldcvt8(Wp + kk * 16);
                acc = __builtin_amdgcn_mfma_f32_32x32x16_bf16(a, b, acc, 0, 0, 0);
            }
#pragma unroll
            for (int r = 0; r < 16; r++) {
                const int row = (r & 3) + 8 * (r >> 2) + 4 * (l >> 5);
                shm[w * 1056 + row * 33 + (l & 31)] = acc[r];
            }
            __syncthreads();
#pragma unroll
            for (int i = 0; i < 4; i++) {
                const int o = i * 256 + t;
                const int row = (o >> 5) & 31, col = o & 31;
                const float v = shm[row * 33 + col] + shm[1056 + row * 33 + col]
                              + shm[2112 + row * 33 + col] + shm[3168 + row * 33 + col];
                E[(size_t)mat * B_ * K_ + (size_t)(b0 + row) * K_ + n0 + col]
                    = fexp2(-LOG2E * v);
            }
        } else {
            const int fid = bid - 256;
            const int mat = fid >> 6, kt = (fid >> 3) & 7, nt = fid & 7;
            const int k0 = kt * 64, n0 = nt * 64;
            const int krow = k0 + (w & 1) * 32 + (l & 31);
            const int ncol = n0 + (w >> 1) * 32 + (l & 31);
            const int dk = (l >> 5) * 8;
            const float* Wm = mat ? W2 : W1;
            const float* ar = kn_t + (size_t)krow * D_;
            const float* br = Wm + (size_t)ncol * KD_ + K_;
            f32x16 acc = ZERO16;
#pragma unroll
            for (int kk = 0; kk < 4; kk++) {
                bf16x8 a = ldcvt8(ar + kk * 16 + dk);
                bf16x8 b = ldcvt8(br + kk * 16 + dk);
                acc = __builtin_amdgcn_mfma_f32_32x32x16_bf16(a, b, acc, 0, 0, 0);
            }
            const int nl_ = (w >> 1) * 32 + (l & 31);
#pragma unroll
            for (int r = 0; r < 16; r++) {
                const int row = (r & 3) + 8 * (r >> 2) + 4 * (l >> 5);
                shm[nl_ * 65 + (w & 1) * 32 + row] = fexp2(-LOG2E * acc[r]);
            }
            __syncthreads();
            float* Fo = mat ? FT2 : FT1;
#pragma unroll
            for (int i = 0; i < 16; i++) {
                const int q = i * 256 + t;
                const int r_ = q >> 6, c_ = q & 63;
                Fo[(size_t)(n0 + r_) * K_ + k0 + c_] = shm[r_ * 65 + c_];
            }
        }
        __syncthreads();   // WAR guard between reps
    }
}

// ---------------------------------------------------------------------------
// kMain (grid (2,32,8), 512 thr), body = R11 v4-verbatim, x REP_M
// ---------------------------------------------------------------------------
__global__ void __launch_bounds__(512) kMain(const float* __restrict__ FT1,
                                             const float* __restrict__ FT2,
                                             const float* __restrict__ Ebase,
                                             const float* __restrict__ W3,
                                             float* __restrict__ pPart) {
    __shared__ float es[2][64][8];
    __shared__ float sacc[3][2][16][64];
    const int t = threadIdx.x, l = t & 63, w = t >> 6;
    const int kg = blockIdx.x, bG = blockIdx.y, ns = blockIdx.z;
    const int b0 = bG * 8, n0 = ns * 64;
    const int k = kg * 256 + l * 4;
    const int bh = w & 1, nq = w >> 1;

    for (int rep = 0; rep < REP_M; ++rep) {
        asm volatile("" ::: "memory");
#pragma unroll
        for (int it = 0; it < 2; it++) {
            const int i = it * 512 + t;
            const int n = i & 63, b = (i >> 6) & 7, mat = i >> 9;
            es[mat][n][b] = Ebase[(size_t)mat * B_ * K_ + (size_t)(b0 + b) * K_ + n0 + n];
        }
        __syncthreads();

        const float* f1p = FT1 + (size_t)(n0 + nq * 16) * K_ + k;
        const float* f2p = FT2 + (size_t)(n0 + nq * 16) * K_ + k;
        const float* w3p = W3 + n0 + nq * 16;

        v4f acc[4];
#pragma unroll
        for (int b = 0; b < 4; b++) acc[b] = (v4f){0.f, 0.f, 0.f, 0.f};

#pragma unroll 4
        for (int nl = 0; nl < 16; nl++) {
            const v4f f1 = *(const v4f*)(f1p + (size_t)nl * K_);
            const v4f f2 = *(const v4f*)(f2p + (size_t)nl * K_);
            const float w3n = w3p[nl];
            const v4f e1 = *(const v4f*)&es[0][nq * 16 + nl][bh * 4];
            const v4f e2 = *(const v4f*)&es[1][nq * 16 + nl][bh * 4];
#pragma unroll
            for (int b = 0; b < 4; b++) {
                const v4f pd = e1[b] * f1 + 1.0f;
                const v4f qd = e2[b] * f2 + 1.0f;
                const v4f den = pd * qd;
                const v4f num = (qd - pd) * w3n;
                const float dxy = den.x * den.y, dzw = den.z * den.w;
                const float rxy = frcp(dxy), rzw = frcp(dzw);
                v4f rc;
                rc.x = rxy * den.y; rc.y = rxy * den.x;
                rc.z = rzw * den.w; rc.w = rzw * den.z;
                acc[b] += num * rc;
            }
        }

        if (nq != 0) {
#pragma unroll
            for (int b = 0; b < 4; b++)
#pragma unroll
                for (int c = 0; c < 4; c++)
                    sacc[nq - 1][bh][b * 4 + c][l] = acc[b][c];
        }
        __syncthreads();
        if (nq == 0) {
#pragma unroll
            for (int b = 0; b < 4; b++) {
                v4f s = acc[b];
#pragma unroll
                for (int q = 0; q < 3; q++) {
                    s.x += sacc[q][bh][b * 4 + 0][l];
                    s.y += sacc[q][bh][b * 4 + 1][l];
                    s.z += sacc[q][bh][b * 4 + 2][l];
                    s.w += sacc[q][bh][b * 4 + 3][l];
                }
                *(v4f*)(pPart + ((size_t)ns * B_ + b0 + bh * 4 + b) * K_ + k) = s;
            }
        }
        __syncthreads();   // WAR guard between reps
    }
}

// ---------------------------------------------------------------------------
// kFin (64 blocks x 256), body = R11-verbatim, x REP_FIN
// ---------------------------------------------------------------------------
__global__ void __launch_bounds__(256) kFin(const float* __restrict__ pPart,
                                            const float* __restrict__ kn_emb,
                                            const float* __restrict__ b3,
                                            float* __restrict__ out) {
    const int t = threadIdx.x, l = t & 63, w = t >> 6;
    const int b = blockIdx.x * 4 + w;
    for (int rep = 0; rep < REP_FIN; ++rep) {
        asm volatile("" ::: "memory");
        const float b3v = b3[0];
        const float* ke = kn_emb + (size_t)b * K_;
        float num = 0.f, den = 0.f;
#pragma unroll
        for (int c = 0; c < 8; c++) {
            const int kk = c * 64 + l;
            float sv = 0.f;
#pragma unroll
            for (int s = 0; s < 8; s++)
                sv += pPart[((size_t)s * B_ + b) * K_ + kk];
            const float kv = ke[kk];
            num = fmaf(fsig(sv + b3v), kv, num);
            den += kv;
        }
#pragma unroll
        for (int off = 32; off; off >>= 1) {
            num += __shfl_xor(num, off, 64);
            den += __shfl_xor(den, off, 64);
        }
        if (l == 0) out[b] = num / den;
    }
}

extern "C" void kernel_launch(void* const* d_in, const int* in_sizes, int n_in,
                              void* d_out, int out_size, void* d_ws, size_t ws_size,
                              hipStream_t stream) {
    const int*   stu_id     = (const int*)d_in[0];
    const int*   exer_id    = (const int*)d_in[1];
    const float* kn_emb     = (const float*)d_in[2];
    const float* stu_table  = (const float*)d_in[3];
    const float* exer_table = (const float*)d_in[4];
    const float* kn_table   = (const float*)d_in[5];
    const float* W1         = (const float*)d_in[6];
    const float* W2         = (const float*)d_in[7];
    const float* W3         = (const float*)d_in[8];
    const float* b3         = (const float*)d_in[9];
    float* out = (float*)d_out;

    float* ws = (float*)d_ws;
    float* FT1   = ws;                                 // K*K f
    float* FT2   = FT1 + (size_t)K_ * K_;              // K*K f
    float* E     = FT2 + (size_t)K_ * K_;              // 2*B*K f
    ushort* Sbu  = (ushort*)(E + 2 * (size_t)B_ * K_); // 2*B*K ushorts
    float* pPart = (float*)(Sbu + 2 * (size_t)B_ * K_);// 8*B*K f = 4 MB

    kS<<<64, 256, 0, stream>>>(stu_id, exer_id, stu_table, exer_table,
                               kn_table, Sbu);
    kEF<<<384, 256, 0, stream>>>(Sbu, W1, W2, kn_table, E, FT1, FT2);
    kMain<<<dim3(2, 32, 8), 512, 0, stream>>>(FT1, FT2, E, W3, pPart);
    kFin<<<64, 256, 0, stream>>>(pPart, kn_emb, b3, out);
}

// Round 13
// 36.526 us; speedup vs baseline: 14.8536x; 14.8536x over previous
//
#include <hip/hip_runtime.h>

#define B_ 256
#define K_ 512
#define D_ 64
#define KD_ 576
#define LOG2E 1.44269504088896340736f

typedef float v4f __attribute__((ext_vector_type(4)));
typedef short bf16x8 __attribute__((ext_vector_type(8)));
typedef float f32x16 __attribute__((ext_vector_type(16)));
typedef _Float16 h2 __attribute__((ext_vector_type(2)));

#define ZERO16 {0.f,0.f,0.f,0.f,0.f,0.f,0.f,0.f,0.f,0.f,0.f,0.f,0.f,0.f,0.f,0.f}

__device__ __forceinline__ float fexp2(float x) {
#if __has_builtin(__builtin_amdgcn_exp2f)
    return __builtin_amdgcn_exp2f(x);
#else
    float r; asm("v_exp_f32 %0, %1" : "=v"(r) : "v"(x)); return r;
#endif
}
__device__ __forceinline__ float frcp(float x) {
#if __has_builtin(__builtin_amdgcn_rcpf)
    return __builtin_amdgcn_rcpf(x);
#else
    float r; asm("v_rcp_f32 %0, %1" : "=v"(r) : "v"(x)); return r;
#endif
}
__device__ __forceinline__ float fsig(float x) {
    return frcp(1.0f + fexp2(-LOG2E * x));
}
__device__ __forceinline__ _Float16 hrcp(_Float16 x) {
    _Float16 r; asm("v_rcp_f16 %0, %1" : "=v"(r) : "v"(x)); return r;
}
__device__ __forceinline__ ushort f2bf(float f) {
    union { float f; unsigned u; } v; v.f = f;
    return (ushort)((v.u + 0x7FFFu + ((v.u >> 16) & 1u)) >> 16);
}
__device__ __forceinline__ unsigned f2h_dup(float x) {
    const _Float16 h = (_Float16)x;
    const h2 p = {h, h};
    return __builtin_bit_cast(unsigned, p);
}
__device__ __forceinline__ unsigned f2h_pair(float a, float b) {
    const h2 p = {(_Float16)a, (_Float16)b};
    return __builtin_bit_cast(unsigned, p);
}
__device__ __forceinline__ bf16x8 ldcvt8(const float* p) {
    float4 a = *(const float4*)p;
    float4 b = *(const float4*)(p + 4);
    bf16x8 r;
    r[0] = (short)f2bf(a.x); r[1] = (short)f2bf(a.y);
    r[2] = (short)f2bf(a.z); r[3] = (short)f2bf(a.w);
    r[4] = (short)f2bf(b.x); r[5] = (short)f2bf(b.y);
    r[6] = (short)f2bf(b.z); r[7] = (short)f2bf(b.w);
    return r;
}

// ---------------------------------------------------------------------------
// kS (64 blocks x 256): Sb[tab][b][n] = bf16(sigmoid(table_row[b] . kn[n]))
// (R7/R11-verbatim)
// ---------------------------------------------------------------------------
__global__ void __launch_bounds__(256) kS(const int* __restrict__ sid,
                                          const int* __restrict__ eid,
                                          const float* __restrict__ stu_t,
                                          const float* __restrict__ exer_t,
                                          const float* __restrict__ kn_t,
                                          ushort* __restrict__ Sbu) {
    const int bid = blockIdx.x, t = threadIdx.x;
    const int l = t & 63, w = t >> 6;
    const int dk = (l >> 5) * 8;
    const int tab = bid >> 5, bt = (bid >> 3) & 3, nt = bid & 7;
    const int b0 = bt * 64, n0 = nt * 64;
    const int brow = b0 + (w & 1) * 32 + (l & 31);
    const int ncol = n0 + (w >> 1) * 32 + (l & 31);
    const int id = (tab ? eid : sid)[brow];
    const float* ar = (tab ? exer_t : stu_t) + (size_t)id * D_;
    const float* br = kn_t + (size_t)ncol * D_;
    f32x16 acc = ZERO16;
#pragma unroll
    for (int kk = 0; kk < 4; kk++) {
        bf16x8 a = ldcvt8(ar + kk * 16 + dk);
        bf16x8 b = ldcvt8(br + kk * 16 + dk);
        acc = __builtin_amdgcn_mfma_f32_32x32x16_bf16(a, b, acc, 0, 0, 0);
    }
    ushort* So = Sbu + (size_t)tab * B_ * K_;
#pragma unroll
    for (int r = 0; r < 16; r++) {
        const int row = (r & 3) + 8 * (r >> 2) + 4 * (l >> 5);
        So[(size_t)(b0 + (w & 1) * 32 + row) * K_ + ncol] = f2bf(fsig(acc[r]));
    }
}

// ---------------------------------------------------------------------------
// kEF (384 blocks x 256):
//  [0,256):   E[mat][b][n] = exp(-(S[b,:] . W[n,0:K]))  f32   (R7-verbatim)
//  [256,384): FTh[mat][n][k/2] = packed-f16 exp(-(kn[k] . W[n,K:K+D]))
//             (LDS transpose, then cvt+pack pairs on store)
// ---------------------------------------------------------------------------
__global__ void __launch_bounds__(256) kEF(const ushort* __restrict__ Sbu,
                                           const float* __restrict__ W1,
                                           const float* __restrict__ W2,
                                           const float* __restrict__ kn_t,
                                           float* __restrict__ E,
                                           unsigned* __restrict__ FT1h,
                                           unsigned* __restrict__ FT2h) {
    __shared__ float shm[4224];
    const int bid = blockIdx.x, t = threadIdx.x;
    const int l = t & 63, w = t >> 6;
    if (bid < 256) {
        const int mat = bid >> 7, bt = (bid >> 4) & 7, nt = bid & 15;
        const int b0 = bt * 32, n0 = nt * 32;
        const int arow = b0 + (l & 31);
        const int nrow = n0 + (l & 31);
        const int koff = w * 128 + (l >> 5) * 8;
        const short* Sp = (const short*)Sbu + (size_t)(mat * B_ + arow) * K_ + koff;
        const float* Wp = (mat ? W2 : W1) + (size_t)nrow * KD_ + koff;
        f32x16 acc = ZERO16;
#pragma unroll
        for (int kk = 0; kk < 8; kk++) {
            bf16x8 a = *(const bf16x8*)(Sp + kk * 16);
            bf16x8 b = ldcvt8(Wp + kk * 16);
            acc = __builtin_amdgcn_mfma_f32_32x32x16_bf16(a, b, acc, 0, 0, 0);
        }
#pragma unroll
        for (int r = 0; r < 16; r++) {
            const int row = (r & 3) + 8 * (r >> 2) + 4 * (l >> 5);
            shm[w * 1056 + row * 33 + (l & 31)] = acc[r];
        }
        __syncthreads();
#pragma unroll
        for (int i = 0; i < 4; i++) {
            const int o = i * 256 + t;
            const int row = (o >> 5) & 31, col = o & 31;
            const float v = shm[row * 33 + col] + shm[1056 + row * 33 + col]
                          + shm[2112 + row * 33 + col] + shm[3168 + row * 33 + col];
            E[(size_t)mat * B_ * K_ + (size_t)(b0 + row) * K_ + n0 + col]
                = fexp2(-LOG2E * v);
        }
    } else {
        const int fid = bid - 256;
        const int mat = fid >> 6, kt = (fid >> 3) & 7, nt = fid & 7;
        const int k0 = kt * 64, n0 = nt * 64;
        const int krow = k0 + (w & 1) * 32 + (l & 31);
        const int ncol = n0 + (w >> 1) * 32 + (l & 31);
        const int dk = (l >> 5) * 8;
        const float* Wm = mat ? W2 : W1;
        const float* ar = kn_t + (size_t)krow * D_;
        const float* br = Wm + (size_t)ncol * KD_ + K_;
        f32x16 acc = ZERO16;
#pragma unroll
        for (int kk = 0; kk < 4; kk++) {
            bf16x8 a = ldcvt8(ar + kk * 16 + dk);
            bf16x8 b = ldcvt8(br + kk * 16 + dk);
            acc = __builtin_amdgcn_mfma_f32_32x32x16_bf16(a, b, acc, 0, 0, 0);
        }
        const int nl_ = (w >> 1) * 32 + (l & 31);
#pragma unroll
        for (int r = 0; r < 16; r++) {
            const int row = (r & 3) + 8 * (r >> 2) + 4 * (l >> 5);
            shm[nl_ * 65 + (w & 1) * 32 + row] = fexp2(-LOG2E * acc[r]);
        }
        __syncthreads();
        unsigned* Fo = mat ? FT2h : FT1h;
#pragma unroll
        for (int i = 0; i < 8; i++) {
            const int q = i * 256 + t;               // 2048 u32 = 64 rows x 32
            const int r_ = q >> 5, c_ = q & 31;
            Fo[(size_t)(n0 + r_) * (K_ / 2) + (k0 >> 1) + c_] =
                f2h_pair(shm[r_ * 65 + 2 * c_], shm[r_ * 65 + 2 * c_ + 1]);
        }
    }
}

// ---------------------------------------------------------------------------
// kMain f16: grid (2 kg, 64 bG, 8 ns) = 1024 blocks (4/CU), 512 thr (8 waves).
// Lane owns 4 k as 2 packed-f16 pairs (uint2 load); 4 b via dup-packed e
// broadcast (1 ds_read_b128/mat); w3 dup-packed b32 broadcast.
// Per packed pair: pk_fma x2, pk_mul, pk_sub+pk_mul, 2x v_rcp_f16, pk_fma.
// f16 window accumulate over 8 n/wave -> f32 expand -> LDS cross-wave reduce.
// ---------------------------------------------------------------------------
__global__ void __launch_bounds__(512) kMain(const unsigned* __restrict__ FT1h,
                                             const unsigned* __restrict__ FT2h,
                                             const float* __restrict__ Ebase,
                                             const float* __restrict__ W3,
                                             float* __restrict__ pPart) {
    __shared__ unsigned es[2][64][4];    // dup-packed f16 e-values, 2 KB
    __shared__ unsigned w3s[64];         // dup-packed f16 w3, 256 B
    __shared__ float sacc[4][4][64][8];  // [b][c][lane][wave], 32 KB
    const int t = threadIdx.x, l = t & 63, w = t >> 6;
    const int kg = blockIdx.x, bG = blockIdx.y, ns = blockIdx.z;
    const int b0 = bG * 4, n0 = ns * 64;

    {   // es fill: coalesced E reads (64-lane runs over n)
        const int n = t & 63, b = (t >> 6) & 3, mat = t >> 8;
        const float ev = Ebase[(size_t)mat * B_ * K_ + (size_t)(b0 + b) * K_ + n0 + n];
        es[mat][n][b] = f2h_dup(ev);
    }
    if (t < 64) w3s[t] = f2h_dup(W3[n0 + t]);
    __syncthreads();

    const int kq = kg * 128 + l * 2;     // uint index; k = 2*kq .. 2*kq+3
    const unsigned* f1p = FT1h + (size_t)n0 * (K_ / 2) + kq;
    const unsigned* f2p = FT2h + (size_t)n0 * (K_ / 2) + kq;

    const h2 one2 = {(_Float16)1.0f, (_Float16)1.0f};
    h2 acc[4][2];
#pragma unroll
    for (int b = 0; b < 4; b++) {
        acc[b][0] = (h2){(_Float16)0.0f, (_Float16)0.0f};
        acc[b][1] = (h2){(_Float16)0.0f, (_Float16)0.0f};
    }

    const int nbase = w * 8;
#pragma unroll
    for (int nl = 0; nl < 8; nl++) {
        const int n = nbase + nl;
        const uint2 f1r = *(const uint2*)(f1p + (size_t)n * (K_ / 2));
        const uint2 f2r = *(const uint2*)(f2p + (size_t)n * (K_ / 2));
        const h2 f1a = __builtin_bit_cast(h2, f1r.x);
        const h2 f1b = __builtin_bit_cast(h2, f1r.y);
        const h2 f2a = __builtin_bit_cast(h2, f2r.x);
        const h2 f2b = __builtin_bit_cast(h2, f2r.y);
        const h2 w3h = __builtin_bit_cast(h2, w3s[n]);
        const uint4 e1r = *(const uint4*)&es[0][n][0];   // broadcast
        const uint4 e2r = *(const uint4*)&es[1][n][0];
        const unsigned e1u[4] = {e1r.x, e1r.y, e1r.z, e1r.w};
        const unsigned e2u[4] = {e2r.x, e2r.y, e2r.z, e2r.w};
#pragma unroll
        for (int b = 0; b < 4; b++) {
            const h2 e1 = __builtin_bit_cast(h2, e1u[b]);
            const h2 e2 = __builtin_bit_cast(h2, e2u[b]);
            {
                const h2 pd = e1 * f1a + one2;
                const h2 qd = e2 * f2a + one2;
                const h2 den = pd * qd;
                const h2 nw = (qd - pd) * w3h;
                const h2 rc = {hrcp(den.x), hrcp(den.y)};
                acc[b][0] += nw * rc;
            }
            {
                const h2 pd = e1 * f1b + one2;
                const h2 qd = e2 * f2b + one2;
                const h2 den = pd * qd;
                const h2 nw = (qd - pd) * w3h;
                const h2 rc = {hrcp(den.x), hrcp(den.y)};
                acc[b][1] += nw * rc;
            }
        }
    }

    // expand f16 window sums to f32 and park [b][c][lane][wave]
#pragma unroll
    for (int b = 0; b < 4; b++) {
        sacc[b][0][l][w] = (float)acc[b][0].x;
        sacc[b][1][l][w] = (float)acc[b][0].y;
        sacc[b][2][l][w] = (float)acc[b][1].x;
        sacc[b][3][l][w] = (float)acc[b][1].y;
    }
    __syncthreads();
    // cross-wave reduce: 1024 outputs, 2 per thread; coalesced pPart writes
#pragma unroll
    for (int o = 0; o < 2; o++) {
        const int flat = o * 512 + t;
        const int b = flat >> 8, rem = flat & 255, l2 = rem >> 2, c = rem & 3;
        const v4f lo = *(const v4f*)&sacc[b][c][l2][0];
        const v4f hi = *(const v4f*)&sacc[b][c][l2][4];
        const float s = ((lo.x + lo.y) + (lo.z + lo.w))
                      + ((hi.x + hi.y) + (hi.z + hi.w));
        const int k = kg * 256 + l2 * 4 + c;
        pPart[((size_t)ns * B_ + b0 + b) * K_ + k] = s;
    }
}

// ---------------------------------------------------------------------------
// kFin (256 blocks x 256): block = one b.
// out[b] = sum_k sigmoid(sum_{ns<8} pPart + b3) * kn_emb[b,k] / sum_n kn_emb
// ---------------------------------------------------------------------------
__global__ void __launch_bounds__(256) kFin(const float* __restrict__ pPart,
                                            const float* __restrict__ kn_emb,
                                            const float* __restrict__ b3,
                                            float* __restrict__ out) {
    __shared__ float rn[4], rd[4];
    const int t = threadIdx.x, l = t & 63, w = t >> 6;
    const int b = blockIdx.x;
    const float b3v = b3[0];
    float num = 0.f, den = 0.f;
#pragma unroll
    for (int c = 0; c < 2; c++) {
        const int kk = c * 256 + t;
        float sv = 0.f;
#pragma unroll
        for (int s = 0; s < 8; s++)
            sv += pPart[((size_t)s * B_ + b) * K_ + kk];
        const float kv = kn_emb[(size_t)b * K_ + kk];
        num = fmaf(fsig(sv + b3v), kv, num);
        den += kv;
    }
#pragma unroll
    for (int off = 32; off; off >>= 1) {
        num += __shfl_xor(num, off, 64);
        den += __shfl_xor(den, off, 64);
    }
    if (l == 0) { rn[w] = num; rd[w] = den; }
    __syncthreads();
    if (t == 0)
        out[b] = (rn[0] + rn[1] + rn[2] + rn[3]) / (rd[0] + rd[1] + rd[2] + rd[3]);
}

extern "C" void kernel_launch(void* const* d_in, const int* in_sizes, int n_in,
                              void* d_out, int out_size, void* d_ws, size_t ws_size,
                              hipStream_t stream) {
    const int*   stu_id     = (const int*)d_in[0];
    const int*   exer_id    = (const int*)d_in[1];
    const float* kn_emb     = (const float*)d_in[2];
    const float* stu_table  = (const float*)d_in[3];
    const float* exer_table = (const float*)d_in[4];
    const float* kn_table   = (const float*)d_in[5];
    const float* W1         = (const float*)d_in[6];
    const float* W2         = (const float*)d_in[7];
    const float* W3         = (const float*)d_in[8];
    const float* b3         = (const float*)d_in[9];
    float* out = (float*)d_out;

    unsigned* FT1h = (unsigned*)d_ws;                       // K*K/2 u32 = 512 KB
    unsigned* FT2h = FT1h + (size_t)K_ * K_ / 2;            // 512 KB
    float* E       = (float*)(FT2h + (size_t)K_ * K_ / 2);  // 2*B*K f
    ushort* Sbu    = (ushort*)(E + 2 * (size_t)B_ * K_);    // 2*B*K ushorts
    float* pPart   = (float*)(Sbu + 2 * (size_t)B_ * K_);   // 8*B*K f = 4 MB

    kS<<<64, 256, 0, stream>>>(stu_id, exer_id, stu_table, exer_table,
                               kn_table, Sbu);
    kEF<<<384, 256, 0, stream>>>(Sbu, W1, W2, kn_table, E, FT1h, FT2h);
    kMain<<<dim3(2, 64, 8), 512, 0, stream>>>(FT1h, FT2h, E, W3, pPart);
    kFin<<<256, 256, 0, stream>>>(pPart, kn_emb, b3, out);
}